// Round 4
// baseline (218.612 us; speedup 1.0000x reference)
//
#include <hip/hip_runtime.h>

typedef unsigned short u16;
typedef unsigned int   u32;

#define B_    8
#define CIN   256
#define G_    32
#define MID_  320
#define WOUT_ 288
#define EPS_  1e-5f

typedef __attribute__((ext_vector_type(8))) short bf16x8;
typedef __attribute__((ext_vector_type(4))) float f32x4;

__device__ __forceinline__ float b2f(u16 v)  { return __uint_as_float(((u32)v) << 16); }
__device__ __forceinline__ u16   f2bf(float f) {
    u32 u = __float_as_uint(f);
    u += 0x7fffu + ((u >> 16) & 1u);
    return (u16)(u >> 16);
}
__device__ __forceinline__ float ldv(const void* p, int i, int isf32) {
    return isf32 ? ((const float*)p)[i] : b2f(((const u16*)p)[i]);
}

// ---------------- workspace layout (bytes) ----------------
#define OFF_Y     0u               // bf16 [8][320][4096]  20.97 MB
#define OFF_XT    (22u<<20)        // bf16 [8][4096][256]  16.78 MB (dead after conv_k)
#define OFF_WLOC  (22u<<20)        // bf16 [8][4096][288]  18.87 MB (aliases XT; written after conv_k)
#define PAR_OFF   (44u<<20)
#define FLAG_OFF  (PAR_OFF + 0u)
#define BIAS_OFF  (PAR_OFF + 64u)      // f32 [320]
#define S1_OFF    (PAR_OFF + 1344u)    // f32 [320]
#define T1_OFF    (PAR_OFF + 2624u)    // f32 [320]
#define S2_OFF    (PAR_OFF + 3904u)    // f32 [32]
#define T2_OFF    (PAR_OFF + 4032u)    // f32 [32]
#define CB2_OFF   (PAR_OFF + 4160u)    // f32 [288]
#define CW1_OFF   (PAR_OFF + 5312u)    // bf16 [32][320]
#define CW2_OFF   (PAR_OFF + 25792u)   // bf16 [288][32]
#define WC_OFF    (PAR_OFF + 44224u)   // bf16 [320][256]

// =====================================================================
// setup: dtype detect, BN folds, canonical bf16 weights
// =====================================================================
__global__ __launch_bounds__(256) void setup_k(
    const void* __restrict__ w1, const void* __restrict__ b1,
    const void* __restrict__ w2, const void* __restrict__ b2,
    const void* __restrict__ w3, const void* __restrict__ b3,
    const void* __restrict__ bn1g, const void* __restrict__ bn1b,
    const void* __restrict__ bn1m, const void* __restrict__ bn1v,
    const void* __restrict__ cw1,
    const void* __restrict__ bn2g, const void* __restrict__ bn2b,
    const void* __restrict__ bn2m, const void* __restrict__ bn2v,
    const void* __restrict__ cw2, const void* __restrict__ cb2,
    u32* __restrict__ flagws, u16* __restrict__ Wc, float* __restrict__ biasAll,
    float* __restrict__ s1, float* __restrict__ t1,
    u16* __restrict__ cw1c, float* __restrict__ s2, float* __restrict__ t2,
    u16* __restrict__ cw2c, float* __restrict__ cb2f)
{
    __shared__ int sflag;
    const int tid = threadIdx.x;
    if (tid == 0) {
        const u32* p = (const u32*)bn1v;
        int allb = 1;
        #pragma unroll
        for (int i = 0; i < 16; ++i) {
            u32 lo = p[i] & 0xffffu;
            if (lo < 0x3F00u || lo > 0x3FC0u) allb = 0;
        }
        sflag = allb ? 0 : 1;
        if (blockIdx.x == 0) *flagws = (u32)sflag;
    }
    __syncthreads();
    const int isf32 = sflag;

    // Wc[oc][c] = concat rows of w1,w2,w3 (bf16)
    const int gtid = blockIdx.x * 256 + tid;
    for (int idx = gtid; idx < MID_ * CIN; idx += 64 * 256) {
        int oc = idx >> 8, c = idx & 255;
        float v;
        if (oc < 32)       v = ldv(w1, oc * CIN + c, isf32);
        else if (oc < 64)  v = ldv(w2, (oc - 32) * CIN + c, isf32);
        else               v = ldv(w3, (oc - 64) * CIN + c, isf32);
        Wc[idx] = f2bf(v);
    }
    if (blockIdx.x != 0) return;

    for (int oc = tid; oc < MID_; oc += 256) {
        float bb;
        if (oc < 32)       bb = ldv(b1, oc, isf32);
        else if (oc < 64)  bb = ldv(b2, oc - 32, isf32);
        else               bb = ldv(b3, oc - 64, isf32);
        biasAll[oc] = bb;
        float g = ldv(bn1g, oc, isf32), v = ldv(bn1v, oc, isf32);
        float m = ldv(bn1m, oc, isf32), be = ldv(bn1b, oc, isf32);
        float s = g * rsqrtf(v + EPS_);
        s1[oc] = s;
        t1[oc] = be - m * s;
    }
    for (int idx = tid; idx < G_ * MID_; idx += 256)   // cw1c [32][320]
        cw1c[idx] = f2bf(ldv(cw1, idx, isf32));
    for (int g = tid; g < G_; g += 256) {
        float gg = ldv(bn2g, g, isf32), v = ldv(bn2v, g, isf32);
        float m = ldv(bn2m, g, isf32), be = ldv(bn2b, g, isf32);
        float s = gg * rsqrtf(v + EPS_);
        s2[g] = s;
        t2[g] = be - m * s;
    }
    for (int idx = tid; idx < WOUT_ * G_; idx += 256)  // cw2c [288][32]
        cw2c[idx] = f2bf(ldv(cw2, idx, isf32));
    for (int o = tid; o < WOUT_; o += 256)
        cb2f[o] = ldv(cb2, o, isf32);
}

// =====================================================================
// transpose: x[b][c][hw] -> Xt[b][hw][c] (bf16, with dtype cvt)
// =====================================================================
__global__ __launch_bounds__(256) void transpose_k(
    const void* __restrict__ x, const u32* __restrict__ flagp, u16* __restrict__ Xt)
{
    __shared__ u16 tile[64 * 68];
    const int pt = blockIdx.x, ct = blockIdx.y, b = blockIdx.z;
    const int c0 = ct * 64, hw0 = pt * 64;
    const int t = threadIdx.x;
    const int isf32 = (int)*flagp;

    if (isf32) {
        const float* xf = (const float*)x;
        for (int p = 0; p < 8; ++p) {
            int idx = t + 256 * p;
            int i = idx >> 5, j2 = idx & 31;
            float2 v = *(const float2*)&xf[((b * 256 + c0 + i) * 4096) + hw0 + 2 * j2];
            u32 pk = (u32)f2bf(v.x) | ((u32)f2bf(v.y) << 16);
            *(u32*)&tile[i * 68 + 2 * j2] = pk;
        }
    } else {
        const u32* xh = (const u32*)x;
        for (int p = 0; p < 8; ++p) {
            int idx = t + 256 * p;
            int i = idx >> 5, j2 = idx & 31;
            u32 pk = xh[(((b * 256 + c0 + i) * 4096) + hw0) / 2 + j2];
            *(u32*)&tile[i * 68 + 2 * j2] = pk;
        }
    }
    __syncthreads();
    u32* Xtw = (u32*)Xt;
    for (int p = 0; p < 8; ++p) {
        int idx = t + 256 * p;
        int j = idx >> 5, iw = idx & 31;
        u32 pk = (u32)tile[(2 * iw) * 68 + j] | ((u32)tile[(2 * iw + 1) * 68 + j] << 16);
        Xtw[(((b * 4096) + hw0 + j) * 256 + c0) / 2 + iw] = pk;
    }
}

// =====================================================================
// conv_k (MFMA): y[b][320][4096] = Wc[320][256] * X + bias  (bf16 out)
// =====================================================================
__global__ __launch_bounds__(256) void conv_k(
    const u16* __restrict__ Wc, const u16* __restrict__ Xt,
    const float* __restrict__ biasAll, u16* __restrict__ y)
{
    __shared__ u16 As[64 * 264];
    __shared__ u16 Bs[256 * 32];
    const int pt = blockIdx.x, mt5 = blockIdx.y, b = blockIdx.z;
    const int oc0 = mt5 * 64, pxb = pt * 256;
    const int t = threadIdx.x;
    const int lane = t & 63, wv = t >> 6;
    const int l16 = lane & 15, quad = lane >> 4;

    {
        const uint4* wg = (const uint4*)Wc;
        for (int p = 0; p < 8; ++p) {
            int idx = t + 256 * p;
            int row = idx >> 5, ch = idx & 31;
            uint4 v = wg[(oc0 + row) * 32 + ch];
            *(uint4*)&As[row * 264 + ch * 8] = v;
        }
    }
    f32x4 acc[4][4];
    #pragma unroll
    for (int i = 0; i < 4; ++i)
        #pragma unroll
        for (int j = 0; j < 4; ++j) acc[i][j] = (f32x4){0.f, 0.f, 0.f, 0.f};

    for (int ks = 0; ks < 8; ++ks) {
        const int c0 = ks * 32;
        __syncthreads();
        {
            const uint4* xg = (const uint4*)Xt;
            for (int p = 0; p < 4; ++p) {
                int idx = t + 256 * p;
                int px = idx >> 2, ch = idx & 3;
                uint4 v = xg[((b * 4096) + pxb + px) * 32 + ks * 4 + ch];
                *(uint4*)&Bs[px * 32 + ch * 8] = v;
            }
        }
        __syncthreads();
        bf16x8 af[4], bfr[4];
        #pragma unroll
        for (int mt = 0; mt < 4; ++mt)
            af[mt] = *(const bf16x8*)&As[(mt * 16 + l16) * 264 + c0 + quad * 8];
        #pragma unroll
        for (int nt = 0; nt < 4; ++nt)
            bfr[nt] = *(const bf16x8*)&Bs[(wv * 64 + nt * 16 + l16) * 32 + quad * 8];
        #pragma unroll
        for (int mt = 0; mt < 4; ++mt)
            #pragma unroll
            for (int nt = 0; nt < 4; ++nt)
                acc[mt][nt] = __builtin_amdgcn_mfma_f32_16x16x32_bf16(af[mt], bfr[nt], acc[mt][nt], 0, 0, 0);
    }
    float bias_r[4][4];
    #pragma unroll
    for (int mt = 0; mt < 4; ++mt)
        #pragma unroll
        for (int r = 0; r < 4; ++r)
            bias_r[mt][r] = biasAll[oc0 + mt * 16 + quad * 4 + r];
    #pragma unroll
    for (int mt = 0; mt < 4; ++mt) {
        int oc = oc0 + mt * 16 + quad * 4;
        #pragma unroll
        for (int nt = 0; nt < 4; ++nt) {
            int px = pxb + wv * 64 + nt * 16 + l16;
            #pragma unroll
            for (int r = 0; r < 4; ++r)
                y[((b * 320) + oc + r) * 4096 + px] = f2bf(acc[mt][nt][r] + bias_r[mt][r]);
        }
    }
}

// =====================================================================
// wgen_k (fused wgen1+wgen2, MFMA, barrier-light):
//   mid = relu(bn1(concat(x1, unfold(x2))))   (built per 64-k chunk in LDS)
//   aA  = relu(bn2(mid . cw1^T))              (registers -> per-wave LDS relayout)
//   wloc2[b][hw][288] = aA . cw2^T + cb2      (direct register stores)
// One block per (b, h-row); 256 threads; B-fragments loaded from global.
// =====================================================================
__global__ __launch_bounds__(256) void wgen_k(
    const u16* __restrict__ y, const u16* __restrict__ cw1c,
    const float* __restrict__ s1g, const float* __restrict__ t1g,
    const float* __restrict__ s2g, const float* __restrict__ t2g,
    const u16* __restrict__ cw2c, const float* __restrict__ cb2f,
    u16* __restrict__ wloc2)
{
    __shared__ u16 x2slab[32 * 3 * 64];   // [r][i3][w]      12288 B
    __shared__ u16 chunk[64 * 72];        // [w][k] pitch 72  9216 B
    __shared__ float s1s[320], t1s[320];  //                  2560 B
    __shared__ u32 lut[320];              //                  1280 B
    __shared__ u16 aATs[4 * 16 * 40];     // per-wave [px16][40]  5120 B
    const int h = blockIdx.x, b = blockIdx.y;
    const int t = threadIdx.x;
    const int lane = t & 63, wv = t >> 6;
    const int l16 = lane & 15, quad = lane >> 4;
    const int hw0 = h * 64;

    // ---- stage x2 slab (ch 32..63 of y, rows h-1..h+1, reflect) ----
    {
        const u32* yw = (const u32*)y;
        for (int i = t; i < 3072; i += 256) {
            int r = i / 96, rem = i - r * 96;
            int i3 = rem >> 5, pw = rem & 31;
            int hr = h + i3 - 1; hr = hr < 0 ? 1 : (hr > 63 ? 62 : hr);
            u32 v = yw[(((b * 320) + 32 + r) * 4096 + hr * 64) / 2 + pw];
            *(u32*)&x2slab[(r * 3 + i3) * 64 + pw * 2] = v;
        }
    }
    for (int i = t; i < 320; i += 256) { s1s[i] = s1g[i]; t1s[i] = t1g[i]; }
    // unfold LUT: k<32 sentinel; else base=(r*3+i3)*64 and j3
    for (int k = t; k < 320; k += 256) {
        u32 v;
        if (k < 32) v = 0xFFFFFFFFu;
        else {
            int cc = k - 32;
            int r = cc / 9, tt = cc - 9 * r;
            int i3 = tt / 3, j3 = tt - 3 * i3;
            v = (((u32)((r * 3 + i3) * 64)) << 2) | (u32)j3;
        }
        lut[k] = v;
    }
    __syncthreads();

    // ---- wgen1: 5 chunks of 64 k; build then MFMA ----
    const int kp = t >> 3;        // 0..31 (k-pair within chunk)
    const int wb = t & 7;         // w = wb + 8*j
    f32x4 acc0 = {0.f,0.f,0.f,0.f}, acc1 = {0.f,0.f,0.f,0.f};

    for (int ks5 = 0; ks5 < 5; ++ks5) {
        const int kbase = ks5 * 64;
        // build chunk[w][k] (u32-packed pairs)
        #pragma unroll
        for (int j = 0; j < 8; ++j) {
            const int w = wb + 8 * j;
            const int wm = (w == 0) ? 1 : w - 1;
            const int wp = (w == 63) ? 62 : w + 1;
            u16 vv[2];
            #pragma unroll
            for (int e = 0; e < 2; ++e) {
                const int k = kbase + 2 * kp + e;
                u32 lv = lut[k];
                float xval;
                if (lv == 0xFFFFFFFFu)
                    xval = b2f(y[((b * 320) + k) * 4096 + hw0 + w]);
                else {
                    int j3 = (int)(lv & 3u);
                    int base = (int)(lv >> 2);
                    int wj = (j3 == 0) ? wm : ((j3 == 1) ? w : wp);
                    xval = b2f(x2slab[base + wj]);
                }
                vv[e] = f2bf(fmaxf(s1s[k] * xval + t1s[k], 0.f));
            }
            *(u32*)&chunk[w * 72 + kp * 2] = (u32)vv[0] | ((u32)vv[1] << 16);
        }
        __syncthreads();
        // MFMA on the chunk (2 k-steps of 32)
        #pragma unroll
        for (int ks = 0; ks < 2; ++ks) {
            const int k0 = kbase + ks * 32;
            bf16x8 af = *(const bf16x8*)&chunk[(wv * 16 + l16) * 72 + ks * 32 + quad * 8];
            bf16x8 b0 = *(const bf16x8*)&cw1c[l16 * 320 + k0 + quad * 8];
            bf16x8 b1 = *(const bf16x8*)&cw1c[(16 + l16) * 320 + k0 + quad * 8];
            acc0 = __builtin_amdgcn_mfma_f32_16x16x32_bf16(af, b0, acc0, 0, 0, 0);
            acc1 = __builtin_amdgcn_mfma_f32_16x16x32_bf16(af, b1, acc1, 0, 0, 0);
        }
        __syncthreads();
    }

    // ---- bn2 + relu -> per-wave A-layout relayout ----
    u16* aw = &aATs[wv * 16 * 40];
    {
        float sg0 = s2g[l16],      tg0 = t2g[l16];
        float sg1 = s2g[16 + l16], tg1 = t2g[16 + l16];
        #pragma unroll
        for (int r = 0; r < 4; ++r) {
            aw[(quad * 4 + r) * 40 + l16]      = f2bf(fmaxf(sg0 * acc0[r] + tg0, 0.f));
            aw[(quad * 4 + r) * 40 + 16 + l16] = f2bf(fmaxf(sg1 * acc1[r] + tg1, 0.f));
        }
    }
    __syncthreads();
    bf16x8 aaf = *(const bf16x8*)&aw[l16 * 40 + quad * 8];

    // ---- wgen2: 9 chunks of 32 o; direct register stores ----
    const int pxs = wv * 16 + quad * 4;
    for (int nc = 0; nc < 9; ++nc) {
        f32x4 c0 = {0.f,0.f,0.f,0.f}, c1 = {0.f,0.f,0.f,0.f};
        bf16x8 b0 = *(const bf16x8*)&cw2c[(nc * 32 + l16) * 32 + quad * 8];
        bf16x8 b1 = *(const bf16x8*)&cw2c[(nc * 32 + 16 + l16) * 32 + quad * 8];
        c0 = __builtin_amdgcn_mfma_f32_16x16x32_bf16(aaf, b0, c0, 0, 0, 0);
        c1 = __builtin_amdgcn_mfma_f32_16x16x32_bf16(aaf, b1, c1, 0, 0, 0);
        float cb0 = cb2f[nc * 32 + l16];
        float cb1 = cb2f[nc * 32 + 16 + l16];
        #pragma unroll
        for (int r = 0; r < 4; ++r) {
            const u32 base = ((u32)((b * 4096) + hw0 + pxs + r)) * 288u + (u32)(nc * 32);
            wloc2[base + l16]      = f2bf(c0[r] + cb0);
            wloc2[base + 16 + l16] = f2bf(c1[r] + cb1);
        }
    }
}

// =====================================================================
// lconv_k: out[b][g*8+s][hw] = sum_k wloc2[b][hw][g*9+k] * x3[zero-pad 3x3]
// =====================================================================
__global__ __launch_bounds__(256) void lconv_k(
    const u16* __restrict__ y, const u16* __restrict__ wloc2,
    const u32* __restrict__ flagp, void* __restrict__ outv)
{
    __shared__ u16 x3s[8 * 34 * 64];   // [s][row(-1..32)][w]
    const int hf = blockIdx.x, g = blockIdx.y, b = blockIdx.z;
    const int h0 = hf * 32;
    const int t = threadIdx.x;
    const int isf32 = (int)*flagp;

    {
        const u32* yw = (const u32*)y;
        int s = t >> 5, l = t & 31;
        int ch = 64 + g * 8 + s;
        for (int q = 0; q < 34; ++q) {
            int hr = h0 + q - 1;
            u32 v = 0;
            if (hr >= 0 && hr < 64) v = yw[(((b * 320) + ch) * 4096 + hr * 64) / 2 + l];
            *(u32*)&x3s[(s * 34 + q) * 64 + l * 2] = v;
        }
    }
    __syncthreads();

    for (int q = 0; q < 8; ++q) {
        int px = t + 256 * q;
        int hl = px >> 6, w = px & 63;
        float wv9[9];
        const u16* wp = &wloc2[((u32)((b * 4096) + h0 * 64 + px)) * 288u + (u32)(g * 9)];
        #pragma unroll
        for (int k = 0; k < 9; ++k) wv9[k] = b2f(wp[k]);
        #pragma unroll
        for (int s = 0; s < 8; ++s) {
            float acc = 0.f;
            #pragma unroll
            for (int i3 = 0; i3 < 3; ++i3) {
                const u16* rowp = &x3s[(s * 34 + hl + i3) * 64];
                float a0 = (w > 0)  ? b2f(rowp[w - 1]) : 0.f;
                float a1 = b2f(rowp[w]);
                float a2 = (w < 63) ? b2f(rowp[w + 1]) : 0.f;
                acc += wv9[i3 * 3 + 0] * a0 + wv9[i3 * 3 + 1] * a1 + wv9[i3 * 3 + 2] * a2;
            }
            int oidx = ((b * 256) + g * 8 + s) * 4096 + h0 * 64 + px;
            if (isf32) ((float*)outv)[oidx] = acc;
            else       ((u16*)outv)[oidx] = f2bf(acc);
        }
    }
}

// =====================================================================
extern "C" void kernel_launch(void* const* d_in, const int* in_sizes, int n_in,
                              void* d_out, int out_size, void* d_ws, size_t ws_size,
                              hipStream_t stream) {
    (void)in_sizes; (void)n_in; (void)out_size; (void)ws_size;
    char* ws = (char*)d_ws;
    u16*   yb     = (u16*)  (ws + OFF_Y);
    u16*   Xt     = (u16*)  (ws + OFF_XT);
    u16*   wloc2  = (u16*)  (ws + OFF_WLOC);
    u32*   flagws = (u32*)  (ws + FLAG_OFF);
    float* biasAll= (float*)(ws + BIAS_OFF);
    float* s1     = (float*)(ws + S1_OFF);
    float* t1     = (float*)(ws + T1_OFF);
    float* s2     = (float*)(ws + S2_OFF);
    float* t2     = (float*)(ws + T2_OFF);
    float* cb2f   = (float*)(ws + CB2_OFF);
    u16*   cw1c   = (u16*)  (ws + CW1_OFF);
    u16*   cw2c   = (u16*)  (ws + CW2_OFF);
    u16*   Wc     = (u16*)  (ws + WC_OFF);

    hipLaunchKernelGGL(setup_k, dim3(64), dim3(256), 0, stream,
                       d_in[1], d_in[2], d_in[3], d_in[4], d_in[5], d_in[6],
                       d_in[7], d_in[8], d_in[9], d_in[10], d_in[11],
                       d_in[12], d_in[13], d_in[14], d_in[15], d_in[16], d_in[17],
                       flagws, Wc, biasAll, s1, t1, cw1c, s2, t2, cw2c, cb2f);
    hipLaunchKernelGGL(transpose_k, dim3(64, 4, 8), dim3(256), 0, stream,
                       d_in[0], flagws, Xt);
    hipLaunchKernelGGL(conv_k, dim3(16, 5, 8), dim3(256), 0, stream,
                       Wc, Xt, biasAll, yb);
    hipLaunchKernelGGL(wgen_k, dim3(64, 8), dim3(256), 0, stream,
                       yb, cw1c, s1, t1, s2, t2, cw2c, cb2f, wloc2);
    hipLaunchKernelGGL(lconv_k, dim3(2, 32, 8), dim3(256), 0, stream,
                       yb, wloc2, flagws, d_out);
}